// Round 1
// 63.106 us; speedup vs baseline: 1.0105x; 1.0105x over previous
//
#include <hip/hip_runtime.h>
#include <hip/hip_bf16.h>
#include <math.h>

// ---------------------------------------------------------------------------
// adj[b,i,j] = exp(-(x_i-x_j)^T W W^T (x_i-x_j)) + I
//            = exp(-(r_i + r_j - 2 y_i.y_j)) + I,  y = W^T x  (Y = X @ W)
//
// R5: 8-wave (512-thread) blocks on the same 64x64 tile grid.
//  - waves 0-3 compute Yi bands, waves 4-7 compute Yj bands CONCURRENTLY
//    (R4 did them serially with 4 waves).
//  - Y overwrites the X tile in place (A-frags register-loaded before any
//    write, same 16-row band per wave, single instruction stream -> safe).
//    LDS 46.6 KB -> 27.6 KB.
//  - Gram phase swaps MFMA operands (A=Yj rows, B=Yi rows): lane then holds
//    4 consecutive j for a fixed i -> float4 output stores (2 dwordx4 per
//    thread instead of 16 scalar dwords).
//  - r computed from bf16-ROUNDED y; all fp32 sums of bf16^2 products are
//    exact (<=16-bit mantissas) so diagonal q_ii cancels to ~1e-16.
// MFMA semantics D[m][n] = sum_k A[m][k]*B[n][k]; C/D layout col=lane&15,
// row=(lane>>4)*4+v (verified by R3/R4 exact diagonal).
// ---------------------------------------------------------------------------

typedef __attribute__((ext_vector_type(8))) short bf16x8;   // 8 bf16 = 4 VGPRs
typedef __attribute__((ext_vector_type(4))) float f32x4;

#define PITCH 72   // row pitch in bf16: 144 B -> 16B-aligned rows for b128 reads

static __device__ __forceinline__ void store4bf(__hip_bfloat16* p, float4 v) {
    __hip_bfloat16 h[4] = {__float2bfloat16(v.x), __float2bfloat16(v.y),
                           __float2bfloat16(v.z), __float2bfloat16(v.w)};
    *(uint2*)p = *(const uint2*)h;   // 8 B aligned: pitch 144 B, col offset 8k
}

__global__ void __launch_bounds__(512, 4) adj_fused_mfma2(
    const float* __restrict__ X, const float* __restrict__ W,
    float* __restrict__ out, int N)
{
    // sX[0] holds Xi then (in place) Yi; sX[1] holds Xj then Yj.
    __shared__ __hip_bfloat16 sX[2][64][PITCH];
    __shared__ __hip_bfloat16 sWT[64][PITCH];   // [c][k]  (W transposed)
    __shared__ float rs[2][64];                 // [0]=ri, [1]=rj

    const int b    = blockIdx.z;
    const int ib   = blockIdx.y << 6;
    const int jb   = blockIdx.x << 6;
    const bool diag = (ib == jb);
    const int t    = threadIdx.x;
    const int w    = t >> 6;        // wave 0..7
    const int lane = t & 63;
    const int m    = lane & 15;     // frag row/col index within 16
    const int q    = lane >> 4;     // quad 0..3

    const float* __restrict__ Xb = X + (size_t)b * N * 64;

    // ---- stage bf16(W^T), bf16(Xi), bf16(Xj): coalesced float4 reads ----
    const float4* W4  = (const float4*)W;
    const float4* Xi4 = (const float4*)(Xb + (size_t)ib * 64);
    const float4* Xj4 = (const float4*)(Xb + (size_t)jb * 64);
#pragma unroll
    for (int it = 0; it < 2; ++it) {
        const int idx = it * 512 + t;        // float4 index into 64x64 tile
        const int row = idx >> 4;            // 16 float4 per row
        const int c4  = (idx & 15) << 2;
        const float4 wv = W4[idx];           // W[row][c4..c4+3]
        sWT[c4 + 0][row] = __float2bfloat16(wv.x);
        sWT[c4 + 1][row] = __float2bfloat16(wv.y);
        sWT[c4 + 2][row] = __float2bfloat16(wv.z);
        sWT[c4 + 3][row] = __float2bfloat16(wv.w);
        store4bf(&sX[0][row][c4], Xi4[idx]);
        if (!diag) store4bf(&sX[1][row][c4], Xj4[idx]);
    }
    __syncthreads();

    // ---- Y = X @ W via MFMA, in place; r from bf16-rounded values ----
    // Wave w: src = w>>2 (0 -> Yi, 1 -> Yj), 16-row band (w&3)*16.
    {
        const int src  = w >> 2;
        const int band = (w & 3) << 4;
        if (!(diag && src)) {   // diag tiles: waves 4-7 idle here (Yj == Yi)
            const bf16x8 a0 = *(const bf16x8*)&sX[src][band + m][q * 8];
            const bf16x8 a1 = *(const bf16x8*)&sX[src][band + m][q * 8 + 32];
            float p[4] = {0.f, 0.f, 0.f, 0.f};
#pragma unroll
            for (int ci = 0; ci < 4; ++ci) {
                const bf16x8 b0 = *(const bf16x8*)&sWT[(ci << 4) + m][q * 8];
                const bf16x8 b1 = *(const bf16x8*)&sWT[(ci << 4) + m][q * 8 + 32];
                f32x4 acc = {0.f, 0.f, 0.f, 0.f};
                acc = __builtin_amdgcn_mfma_f32_16x16x32_bf16(a0, b0, acc, 0, 0, 0);
                acc = __builtin_amdgcn_mfma_f32_16x16x32_bf16(a1, b1, acc, 0, 0, 0);
                // C-layout: lane holds D[q*4+v][m] -> Y row band+q*4+v, col ci*16+m
#pragma unroll
                for (int v = 0; v < 4; ++v) {
                    const __hip_bfloat16 hb = __float2bfloat16(acc[v]);
                    sX[src][band + q * 4 + v][(ci << 4) + m] = hb;
                    const float f = __bfloat162float(hb);
                    p[v] = fmaf(f, f, p[v]);
                }
            }
            // reduce p[v] over the 16 lanes of this quad -> r for 4 rows
#pragma unroll
            for (int off = 1; off < 16; off <<= 1)
#pragma unroll
                for (int v = 0; v < 4; ++v) p[v] += __shfl_xor(p[v], off, 64);
            if (m == 0)
#pragma unroll
                for (int v = 0; v < 4; ++v) rs[src][band + q * 4 + v] = p[v];
        }
    }
    __syncthreads();

    // ---- Gram + epilogue, swapped operands: A=Yj, B=Yi ----
    // D[j'][i'] = dot(Yj row j', Yi row i'); lane holds j' = jband+q*4+v
    // (4 consecutive output columns -> float4 store), i' = isub*16+m.
    const __hip_bfloat16 (*pYi)[PITCH] = sX[0];
    const __hip_bfloat16 (*pYj)[PITCH] = diag ? sX[0] : sX[1];
    const float* prj = diag ? rs[0] : rs[1];

    const int jband = (w & 3) << 4;   // this wave's 16 output columns
    const int ihalf = w >> 2;         // this wave's 32 output rows

    const bf16x8 ja0 = *(const bf16x8*)&pYj[jband + m][q * 8];
    const bf16x8 ja1 = *(const bf16x8*)&pYj[jband + m][q * 8 + 32];
    float rj[4];
#pragma unroll
    for (int v = 0; v < 4; ++v) rj[v] = prj[jband + (q << 2) + v];

    const size_t obase = (size_t)b * N * N;
#pragma unroll
    for (int s = 0; s < 2; ++s) {
        const int isub   = (ihalf << 1) + s;
        const int ilocal = (isub << 4) + m;
        const bf16x8 ib0 = *(const bf16x8*)&pYi[ilocal][q * 8];
        const bf16x8 ib1 = *(const bf16x8*)&pYi[ilocal][q * 8 + 32];
        f32x4 acc = {0.f, 0.f, 0.f, 0.f};
        acc = __builtin_amdgcn_mfma_f32_16x16x32_bf16(ja0, ib0, acc, 0, 0, 0);
        acc = __builtin_amdgcn_mfma_f32_16x16x32_bf16(ja1, ib1, acc, 0, 0, 0);
        const float riv = rs[0][ilocal];
        f32x4 vals;
#pragma unroll
        for (int v = 0; v < 4; ++v) {
            const float qq = riv + rj[v] - 2.f * acc[v];
            float val = __expf(-qq);
            if (diag && ilocal == jband + (q << 2) + v) val += 1.f;  // +I
            vals[v] = val;
        }
        // lane writes 16 B; 4 quads of same m -> 64 B contiguous per row
        *(f32x4*)&out[obase + (size_t)(ib + ilocal) * N + jb + jband + (q << 2)]
            = vals;
    }
}

extern "C" void kernel_launch(void* const* d_in, const int* in_sizes, int n_in,
                              void* d_out, int out_size, void* d_ws, size_t ws_size,
                              hipStream_t stream) {
    (void)n_in; (void)d_ws; (void)ws_size;
    const float* X = (const float*)d_in[0];   // (B, N, 64) fp32
    const float* W = (const float*)d_in[1];   // (64, 64) fp32
    float* out = (float*)d_out;               // (B, N, N) fp32

    const int C  = 64;
    const int BN = in_sizes[0] / C;                                // B*N
    const int N  = (int)(((long long)out_size * C) / in_sizes[0]); // 1024
    const int B  = BN / N;                                         // 2

    adj_fused_mfma2<<<dim3(N / 64, N / 64, B), 512, 0, stream>>>(X, W, out, N);
}